// Round 2
// baseline (2513.010 us; speedup 1.0000x reference)
//
#include <hip/hip_runtime.h>
#include <hip/hip_bf16.h>

#define SEQ   2048
#define DIM   300
#define UU    150
#define G4    600   // 4*U
#define H1    300
#define NSYN  4

typedef _Float16 half2v __attribute__((ext_vector_type(2)));
typedef unsigned u32x4 __attribute__((ext_vector_type(4)));
union HU { unsigned u; half2v h; };

static __device__ __forceinline__ float sigm(float x) { return 1.0f / (1.0f + __expf(-x)); }
static __device__ __forceinline__ float tanh_fast(float x) { return 1.0f - 2.0f / (1.0f + __expf(2.0f * x)); }

// HW dot2: acc += w.x*h.x + w.y*h.y (f16 pairs, f32 accumulate). Both operands
// VGPR (h comes from uniform-address ds_read broadcast, not readlane->SGPR).
static __device__ __forceinline__ float dot2v(unsigned w, unsigned h, float acc) {
    asm("v_dot2_f32_f16 %0, %1, %2, %0" : "+v"(acc) : "v"(w), "v"(h));
    return acc;
}

// LDS-only barrier: drains lgkmcnt (LDS) but NOT vmcnt (fire-and-forget global stores).
#define LDS_BARRIER() asm volatile("s_waitcnt lgkmcnt(0)\n\ts_barrier" ::: "memory")

// ---------------------------------------------------------------------------
// Kernel A: emb = embedding[sentence];  Xpre_dir = emb @ Wk_dir + b_dir
// ---------------------------------------------------------------------------
__global__ void xpre_kernel(const int* __restrict__ sentence,
                            const float* __restrict__ emb_mat,
                            const float* __restrict__ Wk_f,
                            const float* __restrict__ b_f,
                            const float* __restrict__ Wk_b,
                            const float* __restrict__ b_b,
                            float* __restrict__ Xf, float* __restrict__ Xb)
{
    const int dir = blockIdx.y;
    const float* Wk = dir ? Wk_b : Wk_f;
    const float* bb = dir ? b_b : b_f;
    float* X = dir ? Xb : Xf;

    const int s0  = blockIdx.x * 8;
    const int tid = threadIdx.x;

    __shared__ int   sids[8];
    __shared__ float embs[8][DIM];

    if (tid < 8) sids[tid] = sentence[s0 + tid];
    __syncthreads();
    for (int e = tid; e < 8 * DIM; e += 640) {
        int r = e / DIM, d = e - r * DIM;
        embs[r][d] = emb_mat[(long)sids[r] * DIM + d];
    }
    __syncthreads();

    if (tid < G4) {
        float acc[8];
        float bv = bb[tid];
        #pragma unroll
        for (int r = 0; r < 8; ++r) acc[r] = bv;
        for (int k = 0; k < DIM; ++k) {
            float wv = Wk[k * G4 + tid];
            #pragma unroll
            for (int r = 0; r < 8; ++r) acc[r] = fmaf(embs[r][k], wv, acc[r]);
        }
        #pragma unroll
        for (int r = 0; r < 8; ++r) X[(long)(s0 + r) * G4 + tid] = acc[r];
    }
}

// ---------------------------------------------------------------------------
// Kernel B: LSTM scan. 2 blocks (one per direction), 320 threads (5 waves).
//
// Gate-pair decomposition: pair index j = wave*32 + (lane&31), u = j (<150).
//   A-lane (lane<32):  cols u       (i) and u+300 (g)  -> ig = sigm(zi)*tanh(zg)
//   B-lane (lane>=32): cols u+150   (f) and u+450 (o)  -> owns c:
//        c = sigm(zf)*c + shfl_xor(ig,32);  h = sigm(zo)*tanh(c)
// h broadcast: 76 packed-f16 dwords in LDS, uniform-address ds_read_b128
// (HW broadcast, conflict-free). Double-buffered -> ONE barrier per step.
// No z matrix, no readlanes, no dummy columns.
//
// amdgpu_waves_per_eu(2,2): caps VGPR at exactly 256 (512/SIMD / 2 waves).
// R1 lesson: without it the allocator capped at 128 and spilled ~90 regs of
// loop-invariant weights to scratch (VGPR_Count=128, 2214us). (1,1) is NOT
// safe here: >256 VGPRs would make the 2-waves-on-one-SIMD placement of a
// 5-wave block physically impossible.
// ---------------------------------------------------------------------------
#define REP76(F) \
  F(0) F(1) F(2) F(3) F(4) F(5) F(6) F(7) F(8) F(9) \
  F(10) F(11) F(12) F(13) F(14) F(15) F(16) F(17) F(18) F(19) \
  F(20) F(21) F(22) F(23) F(24) F(25) F(26) F(27) F(28) F(29) \
  F(30) F(31) F(32) F(33) F(34) F(35) F(36) F(37) F(38) F(39) \
  F(40) F(41) F(42) F(43) F(44) F(45) F(46) F(47) F(48) F(49) \
  F(50) F(51) F(52) F(53) F(54) F(55) F(56) F(57) F(58) F(59) \
  F(60) F(61) F(62) F(63) F(64) F(65) F(66) F(67) F(68) F(69) \
  F(70) F(71) F(72) F(73) F(74) F(75)

static __device__ __forceinline__ unsigned packpair2(const float* __restrict__ Wr, int c, int k) {
    if (k >= 75) return 0u;   // k is compile-time constant; pad slot stays 0 (no NaN from 0*garbage)
    HU x;
    x.h.x = (_Float16)Wr[(2 * k) * G4 + c];
    x.h.y = (_Float16)Wr[(2 * k + 1) * G4 + c];
    return x.u;
}

__global__ __launch_bounds__(320) __attribute__((amdgpu_waves_per_eu(2, 2)))
void lstm_scan_kernel(
    const float* __restrict__ Xf, const float* __restrict__ Xb,
    const float* __restrict__ Wr_f, const float* __restrict__ Wr_b,
    float* __restrict__ hidden)
{
    const int dir = blockIdx.x;
    const float* X  = dir ? Xb : Xf;
    const float* Wr = dir ? Wr_b : Wr_f;
    const int tid  = threadIdx.x;
    const int l    = tid & 63;
    const int w    = tid >> 6;
    const int isB  = l >> 5;
    const int j    = (w << 5) + (l & 31);
    const bool active = (j < UU);
    const int u    = active ? j : (UU - 1);   // clones of u=149 for the 10 spare pairs in wave 4
    const int cA   = u + isB * UU;            // A: i-col, B: f-col
    const int cB   = cA + 300;                // A: g-col, B: o-col

    // double-buffered packed-f16 h: dword k = (h[2k], h[2k+1]); dwords >=75 stay 0
    __shared__ __align__(16) unsigned hsbuf[2][80];

#define WDECL(k) unsigned wA_##k, wB_##k;
    REP76(WDECL)
#undef WDECL
#define WLOAD(k) wA_##k = packpair2(Wr, cA, k); wB_##k = packpair2(Wr, cB, k);
    REP76(WLOAD)
#undef WLOAD

    for (int e = tid; e < 160; e += 320) ((unsigned*)hsbuf)[e] = 0u;

    float c = 0.0f;
    int tt = dir ? (SEQ - 1) : 0;
    const int dt = dir ? -1 : 1;
    float xA = X[(long)tt * G4 + cA];
    float xB = X[(long)tt * G4 + cB];
    float* hout = hidden + dir * UU + u;
    __syncthreads();   // init visibility (once, outside the loop)

    for (int step = 0; step < SEQ; ++step) {
        const int tn = (step < SEQ - 1) ? (tt + dt) : tt;
        // prefetch next x (consumed next iteration; vmcnt wait overlaps dots)
        float xAn = X[(long)tn * G4 + cA];
        float xBn = X[(long)tn * G4 + cB];

        const u32x4* hb = (const u32x4*)hsbuf[step & 1];
        // chunked broadcast reads (40 dwords live max)
        u32x4 h0 = hb[0], h1 = hb[1], h2 = hb[2], h3 = hb[3], h4 = hb[4];
        u32x4 h5 = hb[5], h6 = hb[6], h7 = hb[7], h8 = hb[8], h9 = hb[9];

        // 4 accumulators: 2 per column, breaks the dependent dot2 chain
        float a0a = xA, a0b = 0.0f, a1a = xB, a1b = 0.0f;

#define DOTQ(k0,k1,k2,k3,hv) \
        a0a = dot2v(wA_##k0, hv.x, a0a); a1a = dot2v(wB_##k0, hv.x, a1a); \
        a0b = dot2v(wA_##k1, hv.y, a0b); a1b = dot2v(wB_##k1, hv.y, a1b); \
        a0a = dot2v(wA_##k2, hv.z, a0a); a1a = dot2v(wB_##k2, hv.z, a1a); \
        a0b = dot2v(wA_##k3, hv.w, a0b); a1b = dot2v(wB_##k3, hv.w, a1b);

        DOTQ(0,1,2,3,h0)     DOTQ(4,5,6,7,h1)     DOTQ(8,9,10,11,h2)
        DOTQ(12,13,14,15,h3) DOTQ(16,17,18,19,h4)
        h0 = hb[10]; h1 = hb[11]; h2 = hb[12]; h3 = hb[13]; h4 = hb[14];
        DOTQ(20,21,22,23,h5) DOTQ(24,25,26,27,h6) DOTQ(28,29,30,31,h7)
        DOTQ(32,33,34,35,h8) DOTQ(36,37,38,39,h9)
        h5 = hb[15]; h6 = hb[16]; h7 = hb[17]; h8 = hb[18];
        DOTQ(40,41,42,43,h0) DOTQ(44,45,46,47,h1) DOTQ(48,49,50,51,h2)
        DOTQ(52,53,54,55,h3) DOTQ(56,57,58,59,h4)
        DOTQ(60,61,62,63,h5) DOTQ(64,65,66,67,h6) DOTQ(68,69,70,71,h7)
        DOTQ(72,73,74,75,h8)
#undef DOTQ

        const float a0 = a0a + a0b;   // A: z_i   B: z_f
        const float a1 = a1a + a1b;   // A: z_g   B: z_o

        // branchless gates (both halves compute; each uses what it needs)
        float s0 = sigm(a0);          // A: sigm(zi)   B: sigm(zf)
        float t1 = tanh_fast(a1);     // A: tanh(zg)
        float s1 = sigm(a1);          //               B: sigm(zo)
        float ig = s0 * t1;           // A-lanes meaningful
        float igx = __shfl_xor(ig, 32);   // B gets partner A's ig (bounded, no NaN)
        c = s0 * c + igx;             // B: sigm(zf)*c + ig  (A's c is bounded garbage, unused)
        float th = tanh_fast(c);
        float hv = s1 * th;           // B: sigm(zo)*tanh(c)

        if (isB && active) {
            ((_Float16*)hsbuf[(step & 1) ^ 1])[u] = (_Float16)hv;  // next-step buffer
            hout[(long)tt * H1] = hv;                               // fire-and-forget
        }
        LDS_BARRIER();   // single barrier per step (double-buffer removes the read/write hazard)

        xA = xAn; xB = xBn; tt = tn;
    }
}

// ---------------------------------------------------------------------------
// Kernel C: out = hidden @ W1 + b1   [2048,300]x[300,300]
// ---------------------------------------------------------------------------
__global__ void w1_kernel(const float* __restrict__ hidden,
                          const float* __restrict__ W1,
                          const float* __restrict__ b1,
                          float* __restrict__ outm)
{
    const int s0  = blockIdx.x * 8;
    const int tid = threadIdx.x;
    __shared__ float hl[8][H1];
    for (int e = tid; e < 8 * H1; e += 320)
        hl[e / H1][e - (e / H1) * H1] = hidden[(long)s0 * H1 + e];
    __syncthreads();

    if (tid < H1) {
        float acc[8];
        float bv = b1[tid];
        #pragma unroll
        for (int r = 0; r < 8; ++r) acc[r] = bv;
        for (int k = 0; k < H1; ++k) {
            float wv = W1[k * H1 + tid];
            #pragma unroll
            for (int r = 0; r < 8; ++r) acc[r] = fmaf(hl[r][k], wv, acc[r]);
        }
        #pragma unroll
        for (int r = 0; r < 8; ++r) outm[(long)(s0 + r) * H1 + tid] = acc[r];
    }
}

// ---------------------------------------------------------------------------
// Block reductions for 320-thread blocks (5 waves)
// ---------------------------------------------------------------------------
static __device__ __forceinline__ float4 blockReduce4(float4 v, float* red, int tid)
{
    #pragma unroll
    for (int off = 32; off > 0; off >>= 1) {
        v.x += __shfl_down(v.x, off);
        v.y += __shfl_down(v.y, off);
        v.z += __shfl_down(v.z, off);
        v.w += __shfl_down(v.w, off);
    }
    __syncthreads();
    if ((tid & 63) == 0) {
        int wv = tid >> 6;
        red[wv * 4 + 0] = v.x; red[wv * 4 + 1] = v.y;
        red[wv * 4 + 2] = v.z; red[wv * 4 + 3] = v.w;
    }
    __syncthreads();
    float4 r;
    r.x = red[0]; r.y = red[1]; r.z = red[2]; r.w = red[3];
    #pragma unroll
    for (int wv = 1; wv < 5; ++wv) {
        r.x += red[wv * 4 + 0]; r.y += red[wv * 4 + 1];
        r.z += red[wv * 4 + 2]; r.w += red[wv * 4 + 3];
    }
    return r;
}

static __device__ __forceinline__ float blockReduce1(float v, float* red, int tid)
{
    #pragma unroll
    for (int off = 32; off > 0; off >>= 1) v += __shfl_down(v, off);
    __syncthreads();
    if ((tid & 63) == 0) red[tid >> 6] = v;
    __syncthreads();
    return red[0] + red[1] + red[2] + red[3] + red[4];
}

// ---------------------------------------------------------------------------
// Kernel D: per-position synonym attention; whh[s][d] = c2[s]*h_hat[s][d]
// ---------------------------------------------------------------------------
__global__ void attn_kernel(const int* __restrict__ sentence,
                            const int* __restrict__ syn_idx,
                            const float* __restrict__ emb_mat,
                            const float* __restrict__ outm,
                            const float* __restrict__ hidden,
                            const float* __restrict__ W2,
                            const float* __restrict__ b2,
                            float* __restrict__ whh)
{
    const int s   = blockIdx.x;
    const int t   = s ? (s - 1) : 0;
    const int tid = threadIdx.x;
    __shared__ float red[20];

    const int sent = sentence[s];
    const long i0 = (long)syn_idx[sent * NSYN + 0] * DIM;
    const long i1 = (long)syn_idx[sent * NSYN + 1] * DIM;
    const long i2 = (long)syn_idx[sent * NSYN + 2] * DIM;
    const long i3 = (long)syn_idx[sent * NSYN + 3] * DIM;

    float se0 = 0.f, se1 = 0.f, se2 = 0.f, se3 = 0.f, od = 0.f, hd = 0.f;
    if (tid < DIM) {
        se0 = emb_mat[i0 + tid];
        se1 = emb_mat[i1 + tid];
        se2 = emb_mat[i2 + tid];
        se3 = emb_mat[i3 + tid];
        od  = outm[(long)t * H1 + tid];
        hd  = hidden[(long)t * H1 + tid];
    }

    float4 dots = blockReduce4(make_float4(se0 * od, se1 * od, se2 * od, se3 * od), red, tid);
    float c0 = __expf(dots.x), c1 = __expf(dots.y), c2c = __expf(dots.z), c3 = __expf(dots.w);

    float hh = fmaf(c0, se0, fmaf(c1, se1, fmaf(c2c, se2, fmaf(c3, se3, hd))));

    float w2v = (tid < DIM) ? W2[tid] : 0.f;
    float dot2 = blockReduce1(hh * w2v, red, tid);
    float cc = __expf(tanh_fast(dot2 + b2[0]));

    if (tid < DIM) whh[(long)s * H1 + tid] = cc * hh;
}

// ---------------------------------------------------------------------------
// Kernel E: H[d] = sum_s whh[s][d]
// ---------------------------------------------------------------------------
__global__ void hred_kernel(const float* __restrict__ whh, float* __restrict__ H)
{
    const int d   = blockIdx.x;
    const int tid = threadIdx.x;
    float acc = 0.f;
    for (int s = tid; s < SEQ; s += 256) acc += whh[(long)s * H1 + d];
    #pragma unroll
    for (int off = 32; off > 0; off >>= 1) acc += __shfl_down(acc, off);
    __shared__ float red[4];
    if ((tid & 63) == 0) red[tid >> 6] = acc;
    __syncthreads();
    if (tid == 0) H[d] = red[0] + red[1] + red[2] + red[3];
}

// ---------------------------------------------------------------------------
// Kernel F: logits
// ---------------------------------------------------------------------------
__global__ void logits_kernel(const float* __restrict__ H,
                              const float* __restrict__ We,
                              const float* __restrict__ be,
                              const float* __restrict__ Ws,
                              const float* __restrict__ bs,
                              float* __restrict__ outp)
{
    const int e = threadIdx.x;
    if (e < 9) {
        float acc = (e < 8) ? be[e] : bs[0];
        for (int d = 0; d < H1; ++d) {
            float wv = (e < 8) ? We[d * 8 + e] : Ws[d];
            acc = fmaf(H[d], wv, acc);
        }
        outp[e] = acc;
    }
}

// ---------------------------------------------------------------------------
extern "C" void kernel_launch(void* const* d_in, const int* in_sizes, int n_in,
                              void* d_out, int out_size, void* d_ws, size_t ws_size,
                              hipStream_t stream)
{
    const int* sentence   = (const int*)d_in[0];
    const int* syn_idx    = (const int*)d_in[1];
    const float* emb      = (const float*)d_in[2];
    const float* Wk_f     = (const float*)d_in[3];
    const float* Wr_f     = (const float*)d_in[4];
    const float* b_f      = (const float*)d_in[5];
    const float* Wk_b     = (const float*)d_in[6];
    const float* Wr_b     = (const float*)d_in[7];
    const float* b_b      = (const float*)d_in[8];
    const float* W1       = (const float*)d_in[9];
    const float* b1       = (const float*)d_in[10];
    const float* W2       = (const float*)d_in[11];
    const float* b2       = (const float*)d_in[12];
    const float* We       = (const float*)d_in[13];
    const float* be       = (const float*)d_in[14];
    const float* Ws       = (const float*)d_in[15];
    const float* bs       = (const float*)d_in[16];

    float* ws     = (float*)d_ws;
    float* Xf     = ws;                      // [2048,600]
    float* Xb     = Xf + (long)SEQ * G4;     // [2048,600]
    float* hidden = Xb + (long)SEQ * G4;     // [2048,300]
    float* outm   = hidden + (long)SEQ * H1; // [2048,300]
    float* whh    = outm + (long)SEQ * H1;   // [2048,300]
    float* H      = whh + (long)SEQ * H1;    // [300]

    float* outp = (float*)d_out;

    xpre_kernel<<<dim3(SEQ / 8, 2), 640, 0, stream>>>(sentence, emb, Wk_f, b_f, Wk_b, b_b, Xf, Xb);
    lstm_scan_kernel<<<2, 320, 0, stream>>>(Xf, Xb, Wr_f, Wr_b, hidden);
    w1_kernel<<<SEQ / 8, 320, 0, stream>>>(hidden, W1, b1, outm);
    attn_kernel<<<SEQ, 320, 0, stream>>>(sentence, syn_idx, emb, outm, hidden, W2, b2, whh);
    hred_kernel<<<H1, 256, 0, stream>>>(whh, H);
    logits_kernel<<<1, 64, 0, stream>>>(H, We, be, Ws, bs, outp);
}

// Round 3
// 2427.813 us; speedup vs baseline: 1.0351x; 1.0351x over previous
//
#include <hip/hip_runtime.h>
#include <hip/hip_bf16.h>

#define SEQ   2048
#define DIM   300
#define UU    150
#define G4    600   // 4*U
#define H1    300
#define NSYN  4

typedef _Float16 half2v __attribute__((ext_vector_type(2)));
typedef unsigned u32x4 __attribute__((ext_vector_type(4)));
union HU { unsigned u; half2v h; };

static __device__ __forceinline__ float sigm(float x) { return 1.0f / (1.0f + __expf(-x)); }
static __device__ __forceinline__ float tanh_fast(float x) { return 1.0f - 2.0f / (1.0f + __expf(2.0f * x)); }

// HW dot2: acc += w.x*h.x + w.y*h.y (f16 pairs, f32 accumulate). Both operands VGPR.
static __device__ __forceinline__ float dot2v(unsigned w, unsigned h, float acc) {
    asm("v_dot2_f32_f16 %0, %1, %2, %0" : "+v"(acc) : "v"(w), "v"(h));
    return acc;
}

// LDS-only barrier: drains lgkmcnt (LDS) but NOT vmcnt (fire-and-forget global stores).
#define LDS_BARRIER() asm volatile("s_waitcnt lgkmcnt(0)\n\ts_barrier" ::: "memory")

// ---------------------------------------------------------------------------
// Kernel A: emb = embedding[sentence];  Xpre_dir = emb @ Wk_dir + b_dir
// ---------------------------------------------------------------------------
__global__ void xpre_kernel(const int* __restrict__ sentence,
                            const float* __restrict__ emb_mat,
                            const float* __restrict__ Wk_f,
                            const float* __restrict__ b_f,
                            const float* __restrict__ Wk_b,
                            const float* __restrict__ b_b,
                            float* __restrict__ Xf, float* __restrict__ Xb)
{
    const int dir = blockIdx.y;
    const float* Wk = dir ? Wk_b : Wk_f;
    const float* bb = dir ? b_b : b_f;
    float* X = dir ? Xb : Xf;

    const int s0  = blockIdx.x * 8;
    const int tid = threadIdx.x;

    __shared__ int   sids[8];
    __shared__ float embs[8][DIM];

    if (tid < 8) sids[tid] = sentence[s0 + tid];
    __syncthreads();
    for (int e = tid; e < 8 * DIM; e += 640) {
        int r = e / DIM, d = e - r * DIM;
        embs[r][d] = emb_mat[(long)sids[r] * DIM + d];
    }
    __syncthreads();

    if (tid < G4) {
        float acc[8];
        float bv = bb[tid];
        #pragma unroll
        for (int r = 0; r < 8; ++r) acc[r] = bv;
        for (int k = 0; k < DIM; ++k) {
            float wv = Wk[k * G4 + tid];
            #pragma unroll
            for (int r = 0; r < 8; ++r) acc[r] = fmaf(embs[r][k], wv, acc[r]);
        }
        #pragma unroll
        for (int r = 0; r < 8; ++r) X[(long)(s0 + r) * G4 + tid] = acc[r];
    }
}

// ---------------------------------------------------------------------------
// Kernel B: LSTM scan. 2 blocks (one per direction), 640 threads (10 waves).
//
// ONE column per thread (R1/R2 lesson: compiler hard-caps this kernel at 128
// VGPRs and spills a 2-col/152-dword weight set; 1 col = 76 weight dwords +
// ~20 live h dwords fits the 128 budget with NO attribute games).
//
// Quad gate layout: quad q = tid>>2 owns unit u=q; lane g = tid&3 owns gate
// column c = g*150+u with gate order i,f,g,o. After the dot phase each lane
// holds z_gate(u). Two quad-local shfl_xor's (DPP quad-perm, ~1cyc) route:
//   act  = (g==2) ? tanh(z) : sigm(z)
//   act2 = shfl_xor(act,2)   // i<->g, f<->o
//   p    = act*act2          // lanes 0,2: sigm(zi)*tanh(zg) = i*g
//   px   = shfl_xor(p,1)     // lane 1 (f-lane) receives i*g
//   lane1: c = sigm(zf)*c + px; h = act2(=sigm(zo)) * tanh(c)
// f-lane is the sole owner/writer of c and h. Non-owner lanes compute bounded
// garbage c (|c| grows at most linearly, tanh_fast saturates, no NaN) and
// never write.
// h broadcast: 76 packed-f16 dwords in LDS, uniform-address ds_read_b128
// (HW broadcast, conflict-free). Double-buffered -> ONE barrier per step.
// ---------------------------------------------------------------------------
#define REP76(F) \
  F(0) F(1) F(2) F(3) F(4) F(5) F(6) F(7) F(8) F(9) \
  F(10) F(11) F(12) F(13) F(14) F(15) F(16) F(17) F(18) F(19) \
  F(20) F(21) F(22) F(23) F(24) F(25) F(26) F(27) F(28) F(29) \
  F(30) F(31) F(32) F(33) F(34) F(35) F(36) F(37) F(38) F(39) \
  F(40) F(41) F(42) F(43) F(44) F(45) F(46) F(47) F(48) F(49) \
  F(50) F(51) F(52) F(53) F(54) F(55) F(56) F(57) F(58) F(59) \
  F(60) F(61) F(62) F(63) F(64) F(65) F(66) F(67) F(68) F(69) \
  F(70) F(71) F(72) F(73) F(74) F(75)

static __device__ __forceinline__ unsigned packpair2(const float* __restrict__ Wr, int c, int k) {
    if (k >= 75) return 0u;   // k is compile-time constant; pad slot stays 0 (pairs with zeroed LDS pad)
    HU x;
    x.h.x = (_Float16)Wr[(2 * k) * G4 + c];
    x.h.y = (_Float16)Wr[(2 * k + 1) * G4 + c];
    return x.u;
}

__global__ __launch_bounds__(640)
void lstm_scan_kernel(
    const float* __restrict__ Xf, const float* __restrict__ Xb,
    const float* __restrict__ Wr_f, const float* __restrict__ Wr_b,
    float* __restrict__ hidden)
{
    const int dir = blockIdx.x;
    const float* X  = dir ? Xb : Xf;
    const float* Wr = dir ? Wr_b : Wr_f;
    const int tid = threadIdx.x;
    const int g   = tid & 3;               // gate: 0=i 1=f 2=g(cell) 3=o
    const int q   = tid >> 2;              // unit index
    const bool active = (q < UU);
    const int u   = active ? q : (UU - 1); // clamp the 10 spare quads in wave 9
    const int col = g * UU + u;

    // double-buffered packed-f16 h: dword k = (h[2k], h[2k+1]); dwords >=75 stay 0
    __shared__ __align__(16) unsigned hsbuf[2][80];

#define WDECL(k) unsigned w_##k;
    REP76(WDECL)
#undef WDECL
#define WLOAD(k) w_##k = packpair2(Wr, col, k);
    REP76(WLOAD)
#undef WLOAD

    for (int e = tid; e < 160; e += 640) ((unsigned*)hsbuf)[e] = 0u;

    float c = 0.0f;
    int tt = dir ? (SEQ - 1) : 0;
    const int dt = dir ? -1 : 1;
    float x = X[(long)tt * G4 + col];
    const bool writer = (g == 1) && active;
    float* hout = hidden + dir * UU + u;   // only dereferenced by writer lanes
    __syncthreads();   // init visibility (once, outside the loop)

    for (int step = 0; step < SEQ; ++step) {
        const int tn = (step < SEQ - 1) ? (tt + dt) : tt;
        // prefetch next x (consumed next iteration; vmcnt wait overlaps dots)
        float xn = X[(long)tn * G4 + col];

        const u32x4* hb = (const u32x4*)hsbuf[step & 1];
        // chunked broadcast reads: max 20 h dwords live at once
        u32x4 h0 = hb[0], h1 = hb[1], h2 = hb[2], h3 = hb[3], h4 = hb[4];

        // 2 accumulators break the dependent dot2 chain
        float aa = x, ab = 0.0f;

#define DOTQ(k0,k1,k2,k3,hv) \
        aa = dot2v(w_##k0, hv.x, aa); ab = dot2v(w_##k1, hv.y, ab); \
        aa = dot2v(w_##k2, hv.z, aa); ab = dot2v(w_##k3, hv.w, ab);

        DOTQ(0,1,2,3,h0)     DOTQ(4,5,6,7,h1)     DOTQ(8,9,10,11,h2)
        DOTQ(12,13,14,15,h3) DOTQ(16,17,18,19,h4)
        h0 = hb[5]; h1 = hb[6]; h2 = hb[7]; h3 = hb[8]; h4 = hb[9];
        DOTQ(20,21,22,23,h0) DOTQ(24,25,26,27,h1) DOTQ(28,29,30,31,h2)
        DOTQ(32,33,34,35,h3) DOTQ(36,37,38,39,h4)
        h0 = hb[10]; h1 = hb[11]; h2 = hb[12]; h3 = hb[13]; h4 = hb[14];
        DOTQ(40,41,42,43,h0) DOTQ(44,45,46,47,h1) DOTQ(48,49,50,51,h2)
        DOTQ(52,53,54,55,h3) DOTQ(56,57,58,59,h4)
        h0 = hb[15]; h1 = hb[16]; h2 = hb[17]; h3 = hb[18];
        DOTQ(60,61,62,63,h0) DOTQ(64,65,66,67,h1) DOTQ(68,69,70,71,h2)
        DOTQ(72,73,74,75,h3)
#undef DOTQ

        const float z = aa + ab;          // this lane's gate pre-activation

        // per-lane activation, then quad routing
        float s  = sigm(z);
        float tz = tanh_fast(z);
        float act  = (g == 2) ? tz : s;       // cndmask, no divergence
        float act2 = __shfl_xor(act, 2);      // i<->g, f<->o
        float p    = act * act2;              // lanes 0,2: i*g product
        float px   = __shfl_xor(p, 1);        // f-lane receives i*g
        c = s * c + px;                       // f-lane: sigm(zf)*c + i*g
        float th = tanh_fast(c);
        float hv = act2 * th;                 // f-lane: sigm(zo)*tanh(c)

        if (writer) {
            ((_Float16*)hsbuf[(step & 1) ^ 1])[u] = (_Float16)hv;  // next-step buffer
            hout[(long)tt * H1] = hv;                               // fire-and-forget
        }
        LDS_BARRIER();   // single barrier per step (double-buffer removes the read/write hazard)

        x = xn; tt = tn;
    }
}

// ---------------------------------------------------------------------------
// Kernel C: out = hidden @ W1 + b1   [2048,300]x[300,300]
// ---------------------------------------------------------------------------
__global__ void w1_kernel(const float* __restrict__ hidden,
                          const float* __restrict__ W1,
                          const float* __restrict__ b1,
                          float* __restrict__ outm)
{
    const int s0  = blockIdx.x * 8;
    const int tid = threadIdx.x;
    __shared__ float hl[8][H1];
    for (int e = tid; e < 8 * H1; e += 320)
        hl[e / H1][e - (e / H1) * H1] = hidden[(long)s0 * H1 + e];
    __syncthreads();

    if (tid < H1) {
        float acc[8];
        float bv = b1[tid];
        #pragma unroll
        for (int r = 0; r < 8; ++r) acc[r] = bv;
        for (int k = 0; k < H1; ++k) {
            float wv = W1[k * H1 + tid];
            #pragma unroll
            for (int r = 0; r < 8; ++r) acc[r] = fmaf(hl[r][k], wv, acc[r]);
        }
        #pragma unroll
        for (int r = 0; r < 8; ++r) outm[(long)(s0 + r) * H1 + tid] = acc[r];
    }
}

// ---------------------------------------------------------------------------
// Block reductions for 320-thread blocks (5 waves)
// ---------------------------------------------------------------------------
static __device__ __forceinline__ float4 blockReduce4(float4 v, float* red, int tid)
{
    #pragma unroll
    for (int off = 32; off > 0; off >>= 1) {
        v.x += __shfl_down(v.x, off);
        v.y += __shfl_down(v.y, off);
        v.z += __shfl_down(v.z, off);
        v.w += __shfl_down(v.w, off);
    }
    __syncthreads();
    if ((tid & 63) == 0) {
        int wv = tid >> 6;
        red[wv * 4 + 0] = v.x; red[wv * 4 + 1] = v.y;
        red[wv * 4 + 2] = v.z; red[wv * 4 + 3] = v.w;
    }
    __syncthreads();
    float4 r;
    r.x = red[0]; r.y = red[1]; r.z = red[2]; r.w = red[3];
    #pragma unroll
    for (int wv = 1; wv < 5; ++wv) {
        r.x += red[wv * 4 + 0]; r.y += red[wv * 4 + 1];
        r.z += red[wv * 4 + 2]; r.w += red[wv * 4 + 3];
    }
    return r;
}

static __device__ __forceinline__ float blockReduce1(float v, float* red, int tid)
{
    #pragma unroll
    for (int off = 32; off > 0; off >>= 1) v += __shfl_down(v, off);
    __syncthreads();
    if ((tid & 63) == 0) red[tid >> 6] = v;
    __syncthreads();
    return red[0] + red[1] + red[2] + red[3] + red[4];
}

// ---------------------------------------------------------------------------
// Kernel D: per-position synonym attention; whh[s][d] = c2[s]*h_hat[s][d]
// ---------------------------------------------------------------------------
__global__ void attn_kernel(const int* __restrict__ sentence,
                            const int* __restrict__ syn_idx,
                            const float* __restrict__ emb_mat,
                            const float* __restrict__ outm,
                            const float* __restrict__ hidden,
                            const float* __restrict__ W2,
                            const float* __restrict__ b2,
                            float* __restrict__ whh)
{
    const int s   = blockIdx.x;
    const int t   = s ? (s - 1) : 0;
    const int tid = threadIdx.x;
    __shared__ float red[20];

    const int sent = sentence[s];
    const long i0 = (long)syn_idx[sent * NSYN + 0] * DIM;
    const long i1 = (long)syn_idx[sent * NSYN + 1] * DIM;
    const long i2 = (long)syn_idx[sent * NSYN + 2] * DIM;
    const long i3 = (long)syn_idx[sent * NSYN + 3] * DIM;

    float se0 = 0.f, se1 = 0.f, se2 = 0.f, se3 = 0.f, od = 0.f, hd = 0.f;
    if (tid < DIM) {
        se0 = emb_mat[i0 + tid];
        se1 = emb_mat[i1 + tid];
        se2 = emb_mat[i2 + tid];
        se3 = emb_mat[i3 + tid];
        od  = outm[(long)t * H1 + tid];
        hd  = hidden[(long)t * H1 + tid];
    }

    float4 dots = blockReduce4(make_float4(se0 * od, se1 * od, se2 * od, se3 * od), red, tid);
    float c0 = __expf(dots.x), c1 = __expf(dots.y), c2c = __expf(dots.z), c3 = __expf(dots.w);

    float hh = fmaf(c0, se0, fmaf(c1, se1, fmaf(c2c, se2, fmaf(c3, se3, hd))));

    float w2v = (tid < DIM) ? W2[tid] : 0.f;
    float dot2 = blockReduce1(hh * w2v, red, tid);
    float cc = __expf(tanh_fast(dot2 + b2[0]));

    if (tid < DIM) whh[(long)s * H1 + tid] = cc * hh;
}

// ---------------------------------------------------------------------------
// Kernel E: H[d] = sum_s whh[s][d]
// ---------------------------------------------------------------------------
__global__ void hred_kernel(const float* __restrict__ whh, float* __restrict__ H)
{
    const int d   = blockIdx.x;
    const int tid = threadIdx.x;
    float acc = 0.f;
    for (int s = tid; s < SEQ; s += 256) acc += whh[(long)s * H1 + d];
    #pragma unroll
    for (int off = 32; off > 0; off >>= 1) acc += __shfl_down(acc, off);
    __shared__ float red[4];
    if ((tid & 63) == 0) red[tid >> 6] = acc;
    __syncthreads();
    if (tid == 0) H[d] = red[0] + red[1] + red[2] + red[3];
}

// ---------------------------------------------------------------------------
// Kernel F: logits
// ---------------------------------------------------------------------------
__global__ void logits_kernel(const float* __restrict__ H,
                              const float* __restrict__ We,
                              const float* __restrict__ be,
                              const float* __restrict__ Ws,
                              const float* __restrict__ bs,
                              float* __restrict__ outp)
{
    const int e = threadIdx.x;
    if (e < 9) {
        float acc = (e < 8) ? be[e] : bs[0];
        for (int d = 0; d < H1; ++d) {
            float wv = (e < 8) ? We[d * 8 + e] : Ws[d];
            acc = fmaf(H[d], wv, acc);
        }
        outp[e] = acc;
    }
}

// ---------------------------------------------------------------------------
extern "C" void kernel_launch(void* const* d_in, const int* in_sizes, int n_in,
                              void* d_out, int out_size, void* d_ws, size_t ws_size,
                              hipStream_t stream)
{
    const int* sentence   = (const int*)d_in[0];
    const int* syn_idx    = (const int*)d_in[1];
    const float* emb      = (const float*)d_in[2];
    const float* Wk_f     = (const float*)d_in[3];
    const float* Wr_f     = (const float*)d_in[4];
    const float* b_f      = (const float*)d_in[5];
    const float* Wk_b     = (const float*)d_in[6];
    const float* Wr_b     = (const float*)d_in[7];
    const float* b_b      = (const float*)d_in[8];
    const float* W1       = (const float*)d_in[9];
    const float* b1       = (const float*)d_in[10];
    const float* W2       = (const float*)d_in[11];
    const float* b2       = (const float*)d_in[12];
    const float* We       = (const float*)d_in[13];
    const float* be       = (const float*)d_in[14];
    const float* Ws       = (const float*)d_in[15];
    const float* bs       = (const float*)d_in[16];

    float* ws     = (float*)d_ws;
    float* Xf     = ws;                      // [2048,600]
    float* Xb     = Xf + (long)SEQ * G4;     // [2048,600]
    float* hidden = Xb + (long)SEQ * G4;     // [2048,300]
    float* outm   = hidden + (long)SEQ * H1; // [2048,300]
    float* whh    = outm + (long)SEQ * H1;   // [2048,300]
    float* H      = whh + (long)SEQ * H1;    // [300]

    float* outp = (float*)d_out;

    xpre_kernel<<<dim3(SEQ / 8, 2), 640, 0, stream>>>(sentence, emb, Wk_f, b_f, Wk_b, b_b, Xf, Xb);
    lstm_scan_kernel<<<2, 640, 0, stream>>>(Xf, Xb, Wr_f, Wr_b, hidden);
    w1_kernel<<<SEQ / 8, 320, 0, stream>>>(hidden, W1, b1, outm);
    attn_kernel<<<SEQ, 320, 0, stream>>>(sentence, syn_idx, emb, outm, hidden, W2, b2, whh);
    hred_kernel<<<H1, 256, 0, stream>>>(whh, H);
    logits_kernel<<<1, 64, 0, stream>>>(H, We, be, Ws, bs, outp);
}